// Round 6
// baseline (204.052 us; speedup 1.0000x reference)
//
#include <hip/hip_runtime.h>
#include <hip/hip_bf16.h>
#include <math.h>

// Output layout (floats):
//  image          [128,3,240,256]   off 0
//  names_idxs     [128,960,256]     off 23592960
//  p              [128,256,256]     off 55050240
//  attributes_idxs[128,240,8]       off 63438848
//  pal            [128,8,12]        off 63684608
#define O_IMG   0
#define O_NAMES 23592960ULL
#define O_P     55050240ULL
#define O_ATTR  63438848ULL
#define O_PAL   63684608ULL

typedef __attribute__((ext_vector_type(8))) short short8v;
typedef __attribute__((ext_vector_type(4))) float f32x4;

static __device__ inline unsigned short f2bf(float x) {
    __hip_bfloat16 h = __float2bfloat16(x);
    return *reinterpret_cast<unsigned short*>(&h);
}

// ---------------- pattern softmax (+ optional bf16 P^T to ws) --------------
template<bool WRITE_PT>
__global__ __launch_bounds__(256) void k_pattern_t(const float* __restrict__ patterns,
                                                   float* __restrict__ out_p,
                                                   unsigned short* __restrict__ Pt) {
    int idx = blockIdx.x * 256 + threadIdx.x;   // b*16384 + row*128 + col
    int col = idx & 127;
    int row = (idx >> 7) & 127;
    int b   = idx >> 14;
    const float* base = patterns + (size_t)b * 65536 + row * 128 + col;
    float v0 = base[0];
    float v1 = base[16384];
    float v2 = base[2 * 16384];
    float v3 = base[3 * 16384];
    float m = fmaxf(fmaxf(v0, v1), fmaxf(v2, v3));
    float e0 = expf(v0 - m), e1 = expf(v1 - m), e2 = expf(v2 - m), e3 = expf(v3 - m);
    float inv = 1.0f / (e0 + e1 + e2 + e3);
    float p0 = e0 * inv, p1 = e1 * inv, p2 = e2 * inv, p3 = e3 * inv;
    int ti = row >> 3, pi = row & 7, tj = col >> 3, pj = col & 7;
    int n  = ti * 16 + tj;
    int px = pi * 8 + pj;
    size_t o = ((size_t)(b * 256 + n) * 64 + px) * 4;
    float4 r; r.x = p0; r.y = p1; r.z = p2; r.w = p3;
    *(float4*)(out_p + o) = r;
    if (WRITE_PT) {
        unsigned short* pt = Pt + (size_t)b * 65536 + (size_t)(px * 4) * 256 + n;
        pt[0]   = f2bf(p0);
        pt[256] = f2bf(p1);
        pt[512] = f2bf(p2);
        pt[768] = f2bf(p3);
    }
}

// ---------------- names softmax, t-coalesced ------------------------------
__global__ __launch_bounds__(256) void k_names(const float* __restrict__ names,
                                               const float* __restrict__ gumbel,
                                               float* __restrict__ out) {
    int chunk = blockIdx.x % 60;
    int b     = blockIdx.x / 60;
    int t0 = chunk * 16;
    __shared__ float sN[256 * 17];

    int q = threadIdx.x;
    const float* nb = names + (size_t)b * 245760 + t0;
    {
        int j  = q & 3;
        int n0 = q >> 2;
        #pragma unroll
        for (int pass = 0; pass < 4; pass++) {
            int n = n0 + 64 * pass;
            float4 v = *(const float4*)(nb + (size_t)n * 960 + 4 * j);
            float* dst = sN + n * 17 + 4 * j;
            dst[0] = v.x; dst[1] = v.y; dst[2] = v.z; dst[3] = v.w;
        }
    }
    __syncthreads();

    int lane = q & 63;
    int w    = q >> 6;
    const float* gb = gumbel + ((size_t)b * 960 + t0) * 256;
    float*       ob = out    + ((size_t)b * 960 + t0) * 256;

    #pragma unroll
    for (int tt = 0; tt < 4; tt++) {
        int t = w * 4 + tt;
        float v[4];
        #pragma unroll
        for (int k = 0; k < 4; k++) {
            int n = lane + 64 * k;
            v[k] = (sN[n * 17 + t] + gb[(size_t)t * 256 + n]) * 0.5f;
        }
        float m = fmaxf(fmaxf(v[0], v[1]), fmaxf(v[2], v[3]));
        #pragma unroll
        for (int off = 1; off < 64; off <<= 1) m = fmaxf(m, __shfl_xor(m, off));
        float s = 0.f;
        #pragma unroll
        for (int k = 0; k < 4; k++) { v[k] = expf(v[k] - m); s += v[k]; }
        #pragma unroll
        for (int off = 1; off < 64; off <<= 1) s += __shfl_xor(s, off);
        float inv = 1.0f / s;
        #pragma unroll
        for (int k = 0; k < 4; k++) ob[(size_t)t * 256 + lane + 64 * k] = v[k] * inv;
    }
}

// ---------------- attr softmax (8-wide) + pal copy -------------------------
__global__ __launch_bounds__(256) void k_attr(const float* __restrict__ attributes,
                                              const float* __restrict__ gumbel,
                                              const float* __restrict__ palettes,
                                              float* __restrict__ out_attr,
                                              float* __restrict__ out_pal) {
    int idx = blockIdx.x * 256 + threadIdx.x;
    if (idx < 12288) out_pal[idx] = palettes[idx];
    if (idx >= 128 * 240) return;
    int tb = idx % 240;
    int b  = idx / 240;
    float v[8];
    float m = -1e30f;
    #pragma unroll
    for (int e = 0; e < 8; e++) {
        v[e] = (attributes[((size_t)b * 8 + e) * 240 + tb] +
                gumbel[((size_t)b * 240 + tb) * 8 + e]) * 0.5f;
        m = fmaxf(m, v[e]);
    }
    float s = 0.f;
    #pragma unroll
    for (int e = 0; e < 8; e++) { v[e] = expf(v[e] - m); s += v[e]; }
    float inv = 1.0f / s;
    float* o = out_attr + (size_t)idx * 8;
    #pragma unroll
    for (int e = 0; e < 8; e++) o[e] = v[e] * inv;
}

// ---------------- MFMA fused GEMM (transposed) + colorize + sigmoid --------
// block = (b, rr): 64 tile-rows t0=rr*64. Computes C^T[f][t] via
// mfma(pt_frag, a_frag, acc) — same loads as before, operands swapped.
// C^T row = f = px*4+g with row-mapping hi*4+rg => one lane's f32x4 holds
// the 4 gray levels of one pixel => colorize is an IN-REGISTER dot.
// Epilogue: zero barriers, zero LDS traffic (sCol read-only).
__global__ __launch_bounds__(256) void k_image_mfma(const float* __restrict__ A,
                                                    const unsigned short* __restrict__ Pt,
                                                    const float* __restrict__ attr,
                                                    const float* __restrict__ pal,
                                                    float* __restrict__ img) {
    // XCD-aware decode: j%8 = XCD; batches b with b%8==x stay on XCD x.
    int j  = blockIdx.x;
    int x  = j & 7;
    int s  = j >> 3;          // 0..239
    int q  = s / 15;
    int rr = s % 15;          // 0..14
    int b  = x + 8 * q;       // 0..127
    int t0 = rr * 64;

    __shared__ __align__(16) char smem[32768];   // sA [64 t][512B] bf16 swizzled
    __shared__ float sColP[16 * 16];             // [tbl][g*3+c], padded to 16

    int tid = threadIdx.x;

    // colorization table (nametable rows 2rr,2rr+1 share attr row rr)
    if (tid < 192) {
        int tbl = tid / 12;
        int gc  = tid % 12;
        int tb  = rr * 16 + tbl;
        const float* at = attr + ((size_t)b * 240 + tb) * 8;
        const float* pl = pal + (size_t)b * 96 + gc;
        float sum = 0.f;
        #pragma unroll
        for (int e = 0; e < 8; e++) sum += at[e] * pl[e * 12];
        sColP[tbl * 16 + gc] = sum;
    }

    // stage A (fp32 -> bf16, swizzled): thread = (t = tid>>2, 64-k chunk)
    {
        const float* Ab = A + ((size_t)b * 960 + t0) * 256;
        int t  = tid >> 2;
        int kb = (tid & 3) * 64;
        #pragma unroll
        for (int jj = 0; jj < 8; jj++) {
            int k = kb + jj * 8;
            float4 u0 = *(const float4*)(Ab + (size_t)t * 256 + k);
            float4 u1 = *(const float4*)(Ab + (size_t)t * 256 + k + 4);
            short8v h;
            h[0] = f2bf(u0.x); h[1] = f2bf(u0.y); h[2] = f2bf(u0.z); h[3] = f2bf(u0.w);
            h[4] = f2bf(u1.x); h[5] = f2bf(u1.y); h[6] = f2bf(u1.z); h[7] = f2bf(u1.w);
            int off = (t * 512 + k * 2) ^ ((t & 7) << 4);
            *(short8v*)(smem + off) = h;
        }
    }
    __syncthreads();   // the ONLY barrier in this kernel

    f32x4 acc[4][4];   // [fi][ti]
    #pragma unroll
    for (int fi = 0; fi < 4; fi++)
        #pragma unroll
        for (int ti = 0; ti < 4; ti++) acc[fi][ti] = (f32x4){0.f, 0.f, 0.f, 0.f};

    int lane = tid & 63;
    int w    = tid >> 6;
    int lo   = lane & 15;
    int hi   = lane >> 4;

    const unsigned short* Ptb = Pt + (size_t)b * 65536 + hi * 8;

    // register-double-buffered Pt fragments (M-operand rows f)
    short8v bcur[4], bnxt[4];
    #pragma unroll
    for (int fi = 0; fi < 4; fi++) {
        int f = w * 64 + fi * 16 + lo;
        bcur[fi] = *(const short8v*)(Ptb + (size_t)f * 256);
    }

    #pragma unroll
    for (int k0 = 0; k0 < 256; k0 += 32) {
        if (k0 < 224) {
            #pragma unroll
            for (int fi = 0; fi < 4; fi++) {
                int f = w * 64 + fi * 16 + lo;
                bnxt[fi] = *(const short8v*)(Ptb + (size_t)f * 256 + k0 + 32);
            }
        }
        int ka = (k0 + hi * 8) * 2;
        short8v a0 = *(short8v*)(smem + (((lo      ) * 512 + ka) ^ ((lo & 7) << 4)));
        short8v a1 = *(short8v*)(smem + (((lo + 16) * 512 + ka) ^ ((lo & 7) << 4)));
        short8v a2 = *(short8v*)(smem + (((lo + 32) * 512 + ka) ^ ((lo & 7) << 4)));
        short8v a3 = *(short8v*)(smem + (((lo + 48) * 512 + ka) ^ ((lo & 7) << 4)));
        #pragma unroll
        for (int fi = 0; fi < 4; fi++) {
            acc[fi][0] = __builtin_amdgcn_mfma_f32_16x16x32_bf16(bcur[fi], a0, acc[fi][0], 0, 0, 0);
            acc[fi][1] = __builtin_amdgcn_mfma_f32_16x16x32_bf16(bcur[fi], a1, acc[fi][1], 0, 0, 0);
            acc[fi][2] = __builtin_amdgcn_mfma_f32_16x16x32_bf16(bcur[fi], a2, acc[fi][2], 0, 0, 0);
            acc[fi][3] = __builtin_amdgcn_mfma_f32_16x16x32_bf16(bcur[fi], a3, acc[fi][3], 0, 0, 0);
        }
        if (k0 < 224) {
            #pragma unroll
            for (int fi = 0; fi < 4; fi++) bcur[fi] = bnxt[fi];
        }
    }

    // epilogue: in-register colorize + sigmoid + store. No barriers.
    float* ib = img + (size_t)b * 184320;   // 3*240*256
    #pragma unroll
    for (int ti = 0; ti < 4; ti++) {
        int tl   = ti * 16 + lo;            // t_local 0..63
        int tbl  = (tl & 31) >> 1;
        float4 c0 = *(float4*)&sColP[tbl * 16 + 0];  // g0c0 g0c1 g0c2 g1c0
        float4 c1 = *(float4*)&sColP[tbl * 16 + 4];  // g1c1 g1c2 g2c0 g2c1
        float4 c2 = *(float4*)&sColP[tbl * 16 + 8];  // g2c2 g3c0 g3c1 g3c2
        int r    = rr * 2 + (tl >> 5);      // nametable row
        int ccol = tl & 31;
        float* tb_ = ib + (size_t)(r * 8) * 256 + ccol * 8;
        #pragma unroll
        for (int fi = 0; fi < 4; fi++) {
            int px = w * 16 + fi * 4 + hi;
            int pi = px >> 3, pj = px & 7;
            f32x4 a4 = acc[fi][ti];
            float s0 = a4[0] * c0.x + a4[1] * c0.w + a4[2] * c1.z + a4[3] * c2.y;
            float s1 = a4[0] * c0.y + a4[1] * c1.x + a4[2] * c1.w + a4[3] * c2.z;
            float s2 = a4[0] * c0.z + a4[1] * c1.y + a4[2] * c2.x + a4[3] * c2.w;
            float y0 = 1.0f / (1.0f + expf(-s0));
            float y1 = 1.0f / (1.0f + expf(-s1));
            float y2 = 1.0f / (1.0f + expf(-s2));
            size_t poff = (size_t)(pi * 256 + pj);
            tb_[poff]              = y0;
            tb_[61440 + poff]      = y1;
            tb_[2 * 61440 + poff]  = y2;
        }
    }
}

// ---------------- fp32 fallback image kernel (no ws) -----------------------
__global__ __launch_bounds__(256) void k_image_fp32(const float* __restrict__ A,
                                                    const float* __restrict__ P,
                                                    const float* __restrict__ attr,
                                                    const float* __restrict__ pal,
                                                    float* __restrict__ img) {
    int blk = blockIdx.x;
    int r = blk % 30;
    int b = blk / 30;
    int t0 = r * 32;

    __shared__ float sA[32][33];
    __shared__ float sB[32][256];
    __shared__ float sColF[16][12];

    int tid = threadIdx.x;
    if (tid < 192) {
        int tbl = tid / 12;
        int gc  = tid % 12;
        int tb  = (r >> 1) * 16 + tbl;
        const float* at = attr + ((size_t)b * 240 + tb) * 8;
        const float* pl = pal + (size_t)b * 96 + gc;
        float s = 0.f;
        #pragma unroll
        for (int e = 0; e < 8; e++) s += at[e] * pl[e * 12];
        sColF[tbl][gc] = s;
    }

    float acc[8][4];
    #pragma unroll
    for (int i = 0; i < 8; i++)
        #pragma unroll
        for (int j = 0; j < 4; j++) acc[i][j] = 0.f;

    int tf = tid & 63;
    int tm = tid >> 6;

    const float* Ab = A + ((size_t)b * 960 + t0) * 256;
    const float* Pb = P + (size_t)b * 65536;

    for (int k0 = 0; k0 < 256; k0 += 32) {
        __syncthreads();
        #pragma unroll
        for (int i = 0; i < 4; i++) {
            int li = tid + i * 256;
            int tl = li >> 5, kk = li & 31;
            sA[tl][kk] = Ab[(size_t)tl * 256 + k0 + kk];
        }
        #pragma unroll
        for (int i = 0; i < 8; i++) {
            int li = tid + i * 256;
            int kk = li >> 6, ff = (li & 63) * 4;
            *(float4*)&sB[kk][ff] = *(const float4*)&Pb[(size_t)(k0 + kk) * 256 + ff];
        }
        __syncthreads();
        #pragma unroll
        for (int kk = 0; kk < 32; kk++) {
            float4 bv = *(float4*)&sB[kk][tf * 4];
            #pragma unroll
            for (int i = 0; i < 8; i++) {
                float av = sA[tm * 8 + i][kk];
                acc[i][0] += av * bv.x;
                acc[i][1] += av * bv.y;
                acc[i][2] += av * bv.z;
                acc[i][3] += av * bv.w;
            }
        }
    }

    int pi = tf >> 3, pj = tf & 7;
    #pragma unroll
    for (int i = 0; i < 8; i++) {
        int cc  = tm * 8 + i;
        int tbl = cc >> 1;
        #pragma unroll
        for (int c = 0; c < 3; c++) {
            float s = acc[i][0] * sColF[tbl][c]
                    + acc[i][1] * sColF[tbl][3 + c]
                    + acc[i][2] * sColF[tbl][6 + c]
                    + acc[i][3] * sColF[tbl][9 + c];
            float y = 1.0f / (1.0f + expf(-s));
            img[(((size_t)b * 3 + c) * 240 + r * 8 + pi) * 256 + cc * 8 + pj] = y;
        }
    }
}

extern "C" void kernel_launch(void* const* d_in, const int* in_sizes, int n_in,
                              void* d_out, int out_size, void* d_ws, size_t ws_size,
                              hipStream_t stream) {
    const float* names       = (const float*)d_in[0];
    const float* patterns    = (const float*)d_in[1];
    const float* attributes  = (const float*)d_in[2];
    const float* palettes    = (const float*)d_in[3];
    const float* gumbel_n    = (const float*)d_in[4];
    const float* gumbel_a    = (const float*)d_in[5];
    float* out = (float*)d_out;

    float* out_img   = out + O_IMG;
    float* out_names = out + O_NAMES;
    float* out_p     = out + O_P;
    float* out_attr  = out + O_ATTR;
    float* out_pal   = out + O_PAL;

    const size_t PT_BYTES = 128ULL * 256 * 256 * 2;   // 16.78 MB bf16 P^T
    bool use_mfma = (ws_size >= PT_BYTES) && (d_ws != nullptr);

    if (use_mfma) {
        unsigned short* Pt = (unsigned short*)d_ws;
        k_pattern_t<true><<<8192, 256, 0, stream>>>(patterns, out_p, Pt);
        k_names<<<128 * 60, 256, 0, stream>>>(names, gumbel_n, out_names);
        k_attr<<<120, 256, 0, stream>>>(attributes, gumbel_a, palettes, out_attr, out_pal);
        k_image_mfma<<<1920, 256, 0, stream>>>(out_names, Pt, out_attr, palettes, out_img);
    } else {
        k_pattern_t<false><<<8192, 256, 0, stream>>>(patterns, out_p, nullptr);
        k_names<<<128 * 60, 256, 0, stream>>>(names, gumbel_n, out_names);
        k_attr<<<120, 256, 0, stream>>>(attributes, gumbel_a, palettes, out_attr, out_pal);
        k_image_fp32<<<128 * 30, 256, 0, stream>>>(out_names, out_p, out_attr, palettes, out_img);
    }
}

// Round 7
// 188.876 us; speedup vs baseline: 1.0803x; 1.0803x over previous
//
#include <hip/hip_runtime.h>
#include <hip/hip_bf16.h>
#include <math.h>

// Output layout (floats):
//  image          [128,3,240,256]   off 0
//  names_idxs     [128,960,256]     off 23592960
//  p              [128,256,256]     off 55050240
//  attributes_idxs[128,240,8]       off 63438848
//  pal            [128,8,12]        off 63684608
#define O_IMG   0
#define O_NAMES 23592960ULL
#define O_P     55050240ULL
#define O_ATTR  63438848ULL
#define O_PAL   63684608ULL

typedef __attribute__((ext_vector_type(8))) short short8v;
typedef __attribute__((ext_vector_type(4))) float f32x4;

static __device__ inline unsigned short f2bf(float x) {
    __hip_bfloat16 h = __float2bfloat16(x);
    return *reinterpret_cast<unsigned short*>(&h);
}

// ---------------- pattern softmax (+ optional bf16 P^T to ws) --------------
template<bool WRITE_PT>
__global__ __launch_bounds__(256) void k_pattern_t(const float* __restrict__ patterns,
                                                   float* __restrict__ out_p,
                                                   unsigned short* __restrict__ Pt) {
    int idx = blockIdx.x * 256 + threadIdx.x;   // b*16384 + row*128 + col
    int col = idx & 127;
    int row = (idx >> 7) & 127;
    int b   = idx >> 14;
    const float* base = patterns + (size_t)b * 65536 + row * 128 + col;
    float v0 = base[0];
    float v1 = base[16384];
    float v2 = base[2 * 16384];
    float v3 = base[3 * 16384];
    float m = fmaxf(fmaxf(v0, v1), fmaxf(v2, v3));
    float e0 = expf(v0 - m), e1 = expf(v1 - m), e2 = expf(v2 - m), e3 = expf(v3 - m);
    float inv = 1.0f / (e0 + e1 + e2 + e3);
    float p0 = e0 * inv, p1 = e1 * inv, p2 = e2 * inv, p3 = e3 * inv;
    int ti = row >> 3, pi = row & 7, tj = col >> 3, pj = col & 7;
    int n  = ti * 16 + tj;
    int px = pi * 8 + pj;
    size_t o = ((size_t)(b * 256 + n) * 64 + px) * 4;
    float4 r; r.x = p0; r.y = p1; r.z = p2; r.w = p3;
    *(float4*)(out_p + o) = r;
    if (WRITE_PT) {
        unsigned short* pt = Pt + (size_t)b * 65536 + (size_t)(px * 4) * 256 + n;
        pt[0]   = f2bf(p0);
        pt[256] = f2bf(p1);
        pt[512] = f2bf(p2);
        pt[768] = f2bf(p3);
    }
}

// ---------------- names softmax, t-coalesced ------------------------------
__global__ __launch_bounds__(256) void k_names(const float* __restrict__ names,
                                               const float* __restrict__ gumbel,
                                               float* __restrict__ out) {
    int chunk = blockIdx.x % 60;
    int b     = blockIdx.x / 60;
    int t0 = chunk * 16;
    __shared__ float sN[256 * 17];

    int q = threadIdx.x;
    const float* nb = names + (size_t)b * 245760 + t0;
    {
        int j  = q & 3;
        int n0 = q >> 2;
        #pragma unroll
        for (int pass = 0; pass < 4; pass++) {
            int n = n0 + 64 * pass;
            float4 v = *(const float4*)(nb + (size_t)n * 960 + 4 * j);
            float* dst = sN + n * 17 + 4 * j;
            dst[0] = v.x; dst[1] = v.y; dst[2] = v.z; dst[3] = v.w;
        }
    }
    __syncthreads();

    int lane = q & 63;
    int w    = q >> 6;
    const float* gb = gumbel + ((size_t)b * 960 + t0) * 256;
    float*       ob = out    + ((size_t)b * 960 + t0) * 256;

    #pragma unroll
    for (int tt = 0; tt < 4; tt++) {
        int t = w * 4 + tt;
        float v[4];
        #pragma unroll
        for (int k = 0; k < 4; k++) {
            int n = lane + 64 * k;
            v[k] = (sN[n * 17 + t] + gb[(size_t)t * 256 + n]) * 0.5f;
        }
        float m = fmaxf(fmaxf(v[0], v[1]), fmaxf(v[2], v[3]));
        #pragma unroll
        for (int off = 1; off < 64; off <<= 1) m = fmaxf(m, __shfl_xor(m, off));
        float s = 0.f;
        #pragma unroll
        for (int k = 0; k < 4; k++) { v[k] = expf(v[k] - m); s += v[k]; }
        #pragma unroll
        for (int off = 1; off < 64; off <<= 1) s += __shfl_xor(s, off);
        float inv = 1.0f / s;
        #pragma unroll
        for (int k = 0; k < 4; k++) ob[(size_t)t * 256 + lane + 64 * k] = v[k] * inv;
    }
}

// ---------------- attr softmax (8-wide) + pal copy -------------------------
__global__ __launch_bounds__(256) void k_attr(const float* __restrict__ attributes,
                                              const float* __restrict__ gumbel,
                                              const float* __restrict__ palettes,
                                              float* __restrict__ out_attr,
                                              float* __restrict__ out_pal) {
    int idx = blockIdx.x * 256 + threadIdx.x;
    if (idx < 12288) out_pal[idx] = palettes[idx];
    if (idx >= 128 * 240) return;
    int tb = idx % 240;
    int b  = idx / 240;
    float v[8];
    float m = -1e30f;
    #pragma unroll
    for (int e = 0; e < 8; e++) {
        v[e] = (attributes[((size_t)b * 8 + e) * 240 + tb] +
                gumbel[((size_t)b * 240 + tb) * 8 + e]) * 0.5f;
        m = fmaxf(m, v[e]);
    }
    float s = 0.f;
    #pragma unroll
    for (int e = 0; e < 8; e++) { v[e] = expf(v[e] - m); s += v[e]; }
    float inv = 1.0f / s;
    float* o = out_attr + (size_t)idx * 8;
    #pragma unroll
    for (int e = 0; e < 8; e++) o[e] = v[e] * inv;
}

// ---------------- k_image helpers ------------------------------------------
__device__ __forceinline__ void loadB4(short8v dst[4], const unsigned short* Ptb,
                                       int w, int lo, int K) {
    #pragma unroll
    for (int fi = 0; fi < 4; fi++) {
        int f = w * 64 + fi * 16 + lo;
        dst[fi] = *(const short8v*)(Ptb + (size_t)f * 256 + K);
    }
}

__device__ __forceinline__ void stepM(f32x4 (&acc)[4][4], const short8v bufB[4],
                                      const char* smem, int lo, int hi, int K) {
    int ka = (K + hi * 8) * 2;
    short8v a0 = *(const short8v*)(smem + (((lo      ) * 512 + ka) ^ ((lo & 7) << 4)));
    short8v a1 = *(const short8v*)(smem + (((lo + 16) * 512 + ka) ^ ((lo & 7) << 4)));
    short8v a2 = *(const short8v*)(smem + (((lo + 32) * 512 + ka) ^ ((lo & 7) << 4)));
    short8v a3 = *(const short8v*)(smem + (((lo + 48) * 512 + ka) ^ ((lo & 7) << 4)));
    #pragma unroll
    for (int ni = 0; ni < 4; ni++) {
        acc[0][ni] = __builtin_amdgcn_mfma_f32_16x16x32_bf16(a0, bufB[ni], acc[0][ni], 0, 0, 0);
        acc[1][ni] = __builtin_amdgcn_mfma_f32_16x16x32_bf16(a1, bufB[ni], acc[1][ni], 0, 0, 0);
        acc[2][ni] = __builtin_amdgcn_mfma_f32_16x16x32_bf16(a2, bufB[ni], acc[2][ni], 0, 0, 0);
        acc[3][ni] = __builtin_amdgcn_mfma_f32_16x16x32_bf16(a3, bufB[ni], acc[3][ni], 0, 0, 0);
    }
}

// ---------------- MFMA fused GEMM + colorize + sigmoid, BM=64 --------------
// Round-5 structure (best) + 2-step-deep 3-buffer register B pipeline:
// at step i, issue loads for step i+2 => ~2 steps (>=L2 latency) of cover.
// No bcur=bnxt copies, no per-iter full vmem drain. Zero K-loop barriers.
__global__ __launch_bounds__(256, 3) void k_image_mfma(const float* __restrict__ A,
                                                       const unsigned short* __restrict__ Pt,
                                                       const float* __restrict__ attr,
                                                       const float* __restrict__ pal,
                                                       float* __restrict__ img) {
    // XCD-aware decode: j%8 = XCD; batches b with b%8==x stay on XCD x.
    int j  = blockIdx.x;
    int x  = j & 7;
    int s  = j >> 3;          // 0..239
    int q  = s / 15;
    int rr = s % 15;          // 0..14
    int b  = x + 8 * q;       // 0..127
    int t0 = rr * 64;

    __shared__ __align__(16) char smem[32768];   // sA [64 t][512B] / sMono [16][260]f
    __shared__ float sCol[192];                  // [16][12]

    int tid  = threadIdx.x;
    int lane = tid & 63;
    int w    = tid >> 6;
    int lo   = lane & 15;
    int hi   = lane >> 4;

    const unsigned short* Ptb = Pt + (size_t)b * 65536 + hi * 8;

    // prologue B loads: issue BEFORE the stage barrier (latency hides under it)
    short8v bA[4], bB[4], bC[4];
    loadB4(bA, Ptb, w, lo, 0);
    loadB4(bB, Ptb, w, lo, 32);

    // colorization table (both nametable rows share attr row rr)
    if (tid < 192) {
        int tbl = tid / 12;
        int gc  = tid % 12;
        int tb  = rr * 16 + tbl;
        const float* at = attr + ((size_t)b * 240 + tb) * 8;
        const float* pl = pal + (size_t)b * 96 + gc;
        float sum = 0.f;
        #pragma unroll
        for (int e = 0; e < 8; e++) sum += at[e] * pl[e * 12];
        sCol[tbl * 12 + gc] = sum;
    }

    // stage A (fp32 -> bf16, swizzled): thread = (t = tid>>2, 64-k chunk)
    {
        const float* Ab = A + ((size_t)b * 960 + t0) * 256;
        int t  = tid >> 2;
        int kb = (tid & 3) * 64;
        #pragma unroll
        for (int jj = 0; jj < 8; jj++) {
            int k = kb + jj * 8;
            float4 u0 = *(const float4*)(Ab + (size_t)t * 256 + k);
            float4 u1 = *(const float4*)(Ab + (size_t)t * 256 + k + 4);
            short8v h;
            h[0] = f2bf(u0.x); h[1] = f2bf(u0.y); h[2] = f2bf(u0.z); h[3] = f2bf(u0.w);
            h[4] = f2bf(u1.x); h[5] = f2bf(u1.y); h[6] = f2bf(u1.z); h[7] = f2bf(u1.w);
            int off = (t * 512 + k * 2) ^ ((t & 7) << 4);
            *(short8v*)(smem + off) = h;
        }
    }
    __syncthreads();

    f32x4 acc[4][4];
    #pragma unroll
    for (int mi = 0; mi < 4; mi++)
        #pragma unroll
        for (int ni = 0; ni < 4; ni++) acc[mi][ni] = (f32x4){0.f, 0.f, 0.f, 0.f};

    // 8 K-steps, 2-deep pipeline, buffers rotate A,B,C
    loadB4(bC, Ptb, w, lo, 64);   stepM(acc, bA, smem, lo, hi, 0);
    loadB4(bA, Ptb, w, lo, 96);   stepM(acc, bB, smem, lo, hi, 32);
    loadB4(bB, Ptb, w, lo, 128);  stepM(acc, bC, smem, lo, hi, 64);
    loadB4(bC, Ptb, w, lo, 160);  stepM(acc, bA, smem, lo, hi, 96);
    loadB4(bA, Ptb, w, lo, 192);  stepM(acc, bB, smem, lo, hi, 128);
    loadB4(bB, Ptb, w, lo, 224);  stepM(acc, bC, smem, lo, hi, 160);
    stepM(acc, bA, smem, lo, hi, 192);
    stepM(acc, bB, smem, lo, hi, 224);

    // epilogue: 4 phases of 16 rows through sMono (overlaid on sA)
    float* sMono = (float*)smem;      // [16][260] padded stride
    int tf = tid & 63;
    int tm = tid >> 6;
    int pi = tf >> 3, pj = tf & 7;

    #pragma unroll
    for (int mi = 0; mi < 4; mi++) {
        __syncthreads();   // prior reads of smem done
        #pragma unroll
        for (int ni = 0; ni < 4; ni++) {
            int colf = w * 64 + ni * 16 + lo;
            #pragma unroll
            for (int rg = 0; rg < 4; rg++)
                sMono[(hi * 4 + rg) * 260 + colf] = acc[mi][ni][rg];
        }
        __syncthreads();
        int r     = rr * 2 + (mi >> 1);     // nametable row
        int cbase = (mi & 1) * 16;          // column base within the row
        #pragma unroll
        for (int i = 0; i < 4; i++) {
            int ccl  = tm * 4 + i;          // 0..15
            int ccol = cbase + ccl;         // 0..31
            int tbl  = ccol >> 1;
            float4 mv = *(float4*)&sMono[ccl * 260 + tf * 4];
            #pragma unroll
            for (int c = 0; c < 3; c++) {
                float sv = mv.x * sCol[tbl * 12 + c]
                         + mv.y * sCol[tbl * 12 + 3 + c]
                         + mv.z * sCol[tbl * 12 + 6 + c]
                         + mv.w * sCol[tbl * 12 + 9 + c];
                float y = 1.0f / (1.0f + expf(-sv));
                img[(((size_t)b * 3 + c) * 240 + r * 8 + pi) * 256 + ccol * 8 + pj] = y;
            }
        }
    }
}

// ---------------- fp32 fallback image kernel (no ws) -----------------------
__global__ __launch_bounds__(256) void k_image_fp32(const float* __restrict__ A,
                                                    const float* __restrict__ P,
                                                    const float* __restrict__ attr,
                                                    const float* __restrict__ pal,
                                                    float* __restrict__ img) {
    int blk = blockIdx.x;
    int r = blk % 30;
    int b = blk / 30;
    int t0 = r * 32;

    __shared__ float sA[32][33];
    __shared__ float sB[32][256];
    __shared__ float sColF[16][12];

    int tid = threadIdx.x;
    if (tid < 192) {
        int tbl = tid / 12;
        int gc  = tid % 12;
        int tb  = (r >> 1) * 16 + tbl;
        const float* at = attr + ((size_t)b * 240 + tb) * 8;
        const float* pl = pal + (size_t)b * 96 + gc;
        float s = 0.f;
        #pragma unroll
        for (int e = 0; e < 8; e++) s += at[e] * pl[e * 12];
        sColF[tbl][gc] = s;
    }

    float acc[8][4];
    #pragma unroll
    for (int i = 0; i < 8; i++)
        #pragma unroll
        for (int j = 0; j < 4; j++) acc[i][j] = 0.f;

    int tf = tid & 63;
    int tm = tid >> 6;

    const float* Ab = A + ((size_t)b * 960 + t0) * 256;
    const float* Pb = P + (size_t)b * 65536;

    for (int k0 = 0; k0 < 256; k0 += 32) {
        __syncthreads();
        #pragma unroll
        for (int i = 0; i < 4; i++) {
            int li = tid + i * 256;
            int tl = li >> 5, kk = li & 31;
            sA[tl][kk] = Ab[(size_t)tl * 256 + k0 + kk];
        }
        #pragma unroll
        for (int i = 0; i < 8; i++) {
            int li = tid + i * 256;
            int kk = li >> 6, ff = (li & 63) * 4;
            *(float4*)&sB[kk][ff] = *(const float4*)&Pb[(size_t)(k0 + kk) * 256 + ff];
        }
        __syncthreads();
        #pragma unroll
        for (int kk = 0; kk < 32; kk++) {
            float4 bv = *(float4*)&sB[kk][tf * 4];
            #pragma unroll
            for (int i = 0; i < 8; i++) {
                float av = sA[tm * 8 + i][kk];
                acc[i][0] += av * bv.x;
                acc[i][1] += av * bv.y;
                acc[i][2] += av * bv.z;
                acc[i][3] += av * bv.w;
            }
        }
    }

    int pi = tf >> 3, pj = tf & 7;
    #pragma unroll
    for (int i = 0; i < 8; i++) {
        int cc  = tm * 8 + i;
        int tbl = cc >> 1;
        #pragma unroll
        for (int c = 0; c < 3; c++) {
            float s = acc[i][0] * sColF[tbl][c]
                    + acc[i][1] * sColF[tbl][3 + c]
                    + acc[i][2] * sColF[tbl][6 + c]
                    + acc[i][3] * sColF[tbl][9 + c];
            float y = 1.0f / (1.0f + expf(-s));
            img[(((size_t)b * 3 + c) * 240 + r * 8 + pi) * 256 + cc * 8 + pj] = y;
        }
    }
}

extern "C" void kernel_launch(void* const* d_in, const int* in_sizes, int n_in,
                              void* d_out, int out_size, void* d_ws, size_t ws_size,
                              hipStream_t stream) {
    const float* names       = (const float*)d_in[0];
    const float* patterns    = (const float*)d_in[1];
    const float* attributes  = (const float*)d_in[2];
    const float* palettes    = (const float*)d_in[3];
    const float* gumbel_n    = (const float*)d_in[4];
    const float* gumbel_a    = (const float*)d_in[5];
    float* out = (float*)d_out;

    float* out_img   = out + O_IMG;
    float* out_names = out + O_NAMES;
    float* out_p     = out + O_P;
    float* out_attr  = out + O_ATTR;
    float* out_pal   = out + O_PAL;

    const size_t PT_BYTES = 128ULL * 256 * 256 * 2;   // 16.78 MB bf16 P^T
    bool use_mfma = (ws_size >= PT_BYTES) && (d_ws != nullptr);

    if (use_mfma) {
        unsigned short* Pt = (unsigned short*)d_ws;
        k_pattern_t<true><<<8192, 256, 0, stream>>>(patterns, out_p, Pt);
        k_names<<<128 * 60, 256, 0, stream>>>(names, gumbel_n, out_names);
        k_attr<<<120, 256, 0, stream>>>(attributes, gumbel_a, palettes, out_attr, out_pal);
        k_image_mfma<<<1920, 256, 0, stream>>>(out_names, Pt, out_attr, palettes, out_img);
    } else {
        k_pattern_t<false><<<8192, 256, 0, stream>>>(patterns, out_p, nullptr);
        k_names<<<128 * 60, 256, 0, stream>>>(names, gumbel_n, out_names);
        k_attr<<<120, 256, 0, stream>>>(attributes, gumbel_a, palettes, out_attr, out_pal);
        k_image_fp32<<<128 * 30, 256, 0, stream>>>(out_names, out_p, out_attr, palettes, out_img);
    }
}

// Round 8
// 168.846 us; speedup vs baseline: 1.2085x; 1.1186x over previous
//
#include <hip/hip_runtime.h>
#include <hip/hip_bf16.h>
#include <math.h>

// Output layout (floats):
//  image          [128,3,240,256]   off 0
//  names_idxs     [128,960,256]     off 23592960
//  p              [128,256,256]     off 55050240
//  attributes_idxs[128,240,8]       off 63438848
//  pal            [128,8,12]        off 63684608
#define O_IMG   0
#define O_NAMES 23592960ULL
#define O_P     55050240ULL
#define O_ATTR  63438848ULL
#define O_PAL   63684608ULL

typedef __attribute__((ext_vector_type(8))) short short8v;
typedef __attribute__((ext_vector_type(4))) float f32x4;

static __device__ inline unsigned short f2bf(float x) {
    __hip_bfloat16 h = __float2bfloat16(x);
    return *reinterpret_cast<unsigned short*>(&h);
}

// ---------------- pattern softmax (+ optional bf16 P^T to ws) --------------
template<bool WRITE_PT>
__global__ __launch_bounds__(256) void k_pattern_t(const float* __restrict__ patterns,
                                                   float* __restrict__ out_p,
                                                   unsigned short* __restrict__ Pt) {
    int idx = blockIdx.x * 256 + threadIdx.x;   // b*16384 + row*128 + col
    int col = idx & 127;
    int row = (idx >> 7) & 127;
    int b   = idx >> 14;
    const float* base = patterns + (size_t)b * 65536 + row * 128 + col;
    float v0 = base[0];
    float v1 = base[16384];
    float v2 = base[2 * 16384];
    float v3 = base[3 * 16384];
    float m = fmaxf(fmaxf(v0, v1), fmaxf(v2, v3));
    float e0 = expf(v0 - m), e1 = expf(v1 - m), e2 = expf(v2 - m), e3 = expf(v3 - m);
    float inv = 1.0f / (e0 + e1 + e2 + e3);
    float p0 = e0 * inv, p1 = e1 * inv, p2 = e2 * inv, p3 = e3 * inv;
    int ti = row >> 3, pi = row & 7, tj = col >> 3, pj = col & 7;
    int n  = ti * 16 + tj;
    int px = pi * 8 + pj;
    size_t o = ((size_t)(b * 256 + n) * 64 + px) * 4;
    float4 r; r.x = p0; r.y = p1; r.z = p2; r.w = p3;
    *(float4*)(out_p + o) = r;
    if (WRITE_PT) {
        unsigned short* pt = Pt + (size_t)b * 65536 + (size_t)(px * 4) * 256 + n;
        pt[0]   = f2bf(p0);
        pt[256] = f2bf(p1);
        pt[512] = f2bf(p2);
        pt[768] = f2bf(p3);
    }
}

// ---------------- names softmax (fallback path only) -----------------------
__global__ __launch_bounds__(256) void k_names(const float* __restrict__ names,
                                               const float* __restrict__ gumbel,
                                               float* __restrict__ out) {
    int chunk = blockIdx.x % 60;
    int b     = blockIdx.x / 60;
    int t0 = chunk * 16;
    __shared__ float sN[256 * 17];

    int q = threadIdx.x;
    const float* nb = names + (size_t)b * 245760 + t0;
    {
        int j  = q & 3;
        int n0 = q >> 2;
        #pragma unroll
        for (int pass = 0; pass < 4; pass++) {
            int n = n0 + 64 * pass;
            float4 v = *(const float4*)(nb + (size_t)n * 960 + 4 * j);
            float* dst = sN + n * 17 + 4 * j;
            dst[0] = v.x; dst[1] = v.y; dst[2] = v.z; dst[3] = v.w;
        }
    }
    __syncthreads();

    int lane = q & 63;
    int w    = q >> 6;
    const float* gb = gumbel + ((size_t)b * 960 + t0) * 256;
    float*       ob = out    + ((size_t)b * 960 + t0) * 256;

    #pragma unroll
    for (int tt = 0; tt < 4; tt++) {
        int t = w * 4 + tt;
        float v[4];
        #pragma unroll
        for (int k = 0; k < 4; k++) {
            int n = lane + 64 * k;
            v[k] = (sN[n * 17 + t] + gb[(size_t)t * 256 + n]) * 0.5f;
        }
        float m = fmaxf(fmaxf(v[0], v[1]), fmaxf(v[2], v[3]));
        #pragma unroll
        for (int off = 1; off < 64; off <<= 1) m = fmaxf(m, __shfl_xor(m, off));
        float s = 0.f;
        #pragma unroll
        for (int k = 0; k < 4; k++) { v[k] = expf(v[k] - m); s += v[k]; }
        #pragma unroll
        for (int off = 1; off < 64; off <<= 1) s += __shfl_xor(s, off);
        float inv = 1.0f / s;
        #pragma unroll
        for (int k = 0; k < 4; k++) ob[(size_t)t * 256 + lane + 64 * k] = v[k] * inv;
    }
}

// ---------------- attr softmax (8-wide) + pal copy -------------------------
__global__ __launch_bounds__(256) void k_attr(const float* __restrict__ attributes,
                                              const float* __restrict__ gumbel,
                                              const float* __restrict__ palettes,
                                              float* __restrict__ out_attr,
                                              float* __restrict__ out_pal) {
    int idx = blockIdx.x * 256 + threadIdx.x;
    if (idx < 12288) out_pal[idx] = palettes[idx];
    if (idx >= 128 * 240) return;
    int tb = idx % 240;
    int b  = idx / 240;
    float v[8];
    float m = -1e30f;
    #pragma unroll
    for (int e = 0; e < 8; e++) {
        v[e] = (attributes[((size_t)b * 8 + e) * 240 + tb] +
                gumbel[((size_t)b * 240 + tb) * 8 + e]) * 0.5f;
        m = fmaxf(m, v[e]);
    }
    float s = 0.f;
    #pragma unroll
    for (int e = 0; e < 8; e++) { v[e] = expf(v[e] - m); s += v[e]; }
    float inv = 1.0f / s;
    float* o = out_attr + (size_t)idx * 8;
    #pragma unroll
    for (int e = 0; e < 8; e++) o[e] = v[e] * inv;
}

// ---------------- FUSED names-softmax + MFMA GEMM + colorize + sigmoid -----
// block = (b, rr): 64 tile-rows t0=rr*64. Phase A computes the 64 softmax
// rows IN-BLOCK (writes fp32 names_idxs output + bf16 swizzled sA in LDS) —
// the 120 MB A re-read through HBM is eliminated. Then round-5 K-loop
// (B frags direct from L2-hot Pt, 1-deep register prefetch, zero barriers)
// and round-5 epilogue.
__global__ __launch_bounds__(256, 3) void k_fused(const float* __restrict__ names,
                                                  const float* __restrict__ gumbel,
                                                  const unsigned short* __restrict__ Pt,
                                                  const float* __restrict__ attr,
                                                  const float* __restrict__ pal,
                                                  float* __restrict__ out_names,
                                                  float* __restrict__ img) {
    // XCD-aware decode: j%8 = XCD; batches b with b%8==x stay on XCD x.
    int j  = blockIdx.x;
    int x  = j & 7;
    int s  = j >> 3;          // 0..239
    int q  = s / 15;
    int rr = s % 15;          // 0..14
    int b  = x + 8 * q;       // 0..127
    int t0 = rr * 64;

    __shared__ __align__(16) char smem[32768];   // sA [64 t][512B] / sMono [16][260]f
    __shared__ float sN[256 * 17];               // names transpose staging (17.4 KB)
    __shared__ float sCol[192];                  // [16][12]

    int tid  = threadIdx.x;
    int lane = tid & 63;
    int w    = tid >> 6;
    int lo   = lane & 15;
    int hi   = lane >> 4;

    // colorization table (both nametable rows share attr row rr)
    if (tid < 192) {
        int tbl = tid / 12;
        int gc  = tid % 12;
        int tb  = rr * 16 + tbl;
        const float* at = attr + ((size_t)b * 240 + tb) * 8;
        const float* pl = pal + (size_t)b * 96 + gc;
        float sum = 0.f;
        #pragma unroll
        for (int e = 0; e < 8; e++) sum += at[e] * pl[e * 12];
        sCol[tbl * 12 + gc] = sum;
    }

    // ---------- phase A: names softmax for 64 t-rows, 4 chunks of 16 ------
    const float* nb  = names + (size_t)b * 245760 + t0;
    const float* gb  = gumbel + ((size_t)b * 960 + t0) * 256;
    float*       onb = out_names + ((size_t)b * 960 + t0) * 256;

    for (int c = 0; c < 4; c++) {
        if (c) __syncthreads();            // prior chunk's sN reads done
        {   // stage names[n][t-window] (one 64B line per n-row)
            int jj = tid & 3;
            int n0 = tid >> 2;
            #pragma unroll
            for (int p = 0; p < 4; p++) {
                int n = n0 + 64 * p;
                float4 v = *(const float4*)(nb + (size_t)n * 960 + c * 16 + 4 * jj);
                float* dst = sN + n * 17 + 4 * jj;
                dst[0] = v.x; dst[1] = v.y; dst[2] = v.z; dst[3] = v.w;
            }
        }
        __syncthreads();
        #pragma unroll
        for (int tt = 0; tt < 4; tt++) {
            int trow = w * 4 + tt;         // row within chunk (0..15)
            int tl   = c * 16 + trow;      // t_local in block (0..63)
            float v[4];
            #pragma unroll
            for (int k = 0; k < 4; k++) {
                int n = lane + 64 * k;
                v[k] = (sN[n * 17 + trow] + gb[(size_t)tl * 256 + n]) * 0.5f;  // /TAU
            }
            float m = fmaxf(fmaxf(v[0], v[1]), fmaxf(v[2], v[3]));
            #pragma unroll
            for (int off = 1; off < 64; off <<= 1) m = fmaxf(m, __shfl_xor(m, off));
            float sm = 0.f;
            #pragma unroll
            for (int k = 0; k < 4; k++) { v[k] = expf(v[k] - m); sm += v[k]; }
            #pragma unroll
            for (int off = 1; off < 64; off <<= 1) sm += __shfl_xor(sm, off);
            float inv = 1.0f / sm;
            #pragma unroll
            for (int k = 0; k < 4; k++) {
                int n = lane + 64 * k;
                float p = v[k] * inv;
                onb[(size_t)tl * 256 + n] = p;                    // fp32 output
                *(unsigned short*)(smem + ((tl * 512 + n * 2) ^ ((tl & 7) << 4))) = f2bf(p);
            }
        }
    }
    __syncthreads();   // sA complete

    // ---------- phase B: K-loop (round-5 structure, 1-deep prefetch) -------
    f32x4 acc[4][4];
    #pragma unroll
    for (int mi = 0; mi < 4; mi++)
        #pragma unroll
        for (int ni = 0; ni < 4; ni++) acc[mi][ni] = (f32x4){0.f, 0.f, 0.f, 0.f};

    const unsigned short* Ptb = Pt + (size_t)b * 65536 + hi * 8;

    short8v bcur[4], bnxt[4];
    #pragma unroll
    for (int ni = 0; ni < 4; ni++) {
        int f = w * 64 + ni * 16 + lo;
        bcur[ni] = *(const short8v*)(Ptb + (size_t)f * 256);
    }

    #pragma unroll
    for (int k0 = 0; k0 < 256; k0 += 32) {
        if (k0 < 224) {
            #pragma unroll
            for (int ni = 0; ni < 4; ni++) {
                int f = w * 64 + ni * 16 + lo;
                bnxt[ni] = *(const short8v*)(Ptb + (size_t)f * 256 + k0 + 32);
            }
        }
        int ka = (k0 + hi * 8) * 2;
        short8v a0 = *(short8v*)(smem + (((lo      ) * 512 + ka) ^ ((lo & 7) << 4)));
        short8v a1 = *(short8v*)(smem + (((lo + 16) * 512 + ka) ^ ((lo & 7) << 4)));
        short8v a2 = *(short8v*)(smem + (((lo + 32) * 512 + ka) ^ ((lo & 7) << 4)));
        short8v a3 = *(short8v*)(smem + (((lo + 48) * 512 + ka) ^ ((lo & 7) << 4)));
        #pragma unroll
        for (int ni = 0; ni < 4; ni++) {
            acc[0][ni] = __builtin_amdgcn_mfma_f32_16x16x32_bf16(a0, bcur[ni], acc[0][ni], 0, 0, 0);
            acc[1][ni] = __builtin_amdgcn_mfma_f32_16x16x32_bf16(a1, bcur[ni], acc[1][ni], 0, 0, 0);
            acc[2][ni] = __builtin_amdgcn_mfma_f32_16x16x32_bf16(a2, bcur[ni], acc[2][ni], 0, 0, 0);
            acc[3][ni] = __builtin_amdgcn_mfma_f32_16x16x32_bf16(a3, bcur[ni], acc[3][ni], 0, 0, 0);
        }
        if (k0 < 224) {
            #pragma unroll
            for (int ni = 0; ni < 4; ni++) bcur[ni] = bnxt[ni];
        }
    }

    // ---------- phase C: epilogue (round-5) --------------------------------
    float* sMono = (float*)smem;      // [16][260] padded stride
    int tf = tid & 63;
    int tm = tid >> 6;
    int pi = tf >> 3, pj = tf & 7;

    #pragma unroll
    for (int mi = 0; mi < 4; mi++) {
        __syncthreads();   // prior reads of smem done
        #pragma unroll
        for (int ni = 0; ni < 4; ni++) {
            int colf = w * 64 + ni * 16 + lo;
            #pragma unroll
            for (int rg = 0; rg < 4; rg++)
                sMono[(hi * 4 + rg) * 260 + colf] = acc[mi][ni][rg];
        }
        __syncthreads();
        int r     = rr * 2 + (mi >> 1);     // nametable row
        int cbase = (mi & 1) * 16;          // column base within the row
        #pragma unroll
        for (int i = 0; i < 4; i++) {
            int ccl  = tm * 4 + i;          // 0..15
            int ccol = cbase + ccl;         // 0..31
            int tbl  = ccol >> 1;
            float4 mv = *(float4*)&sMono[ccl * 260 + tf * 4];
            #pragma unroll
            for (int c = 0; c < 3; c++) {
                float sv = mv.x * sCol[tbl * 12 + c]
                         + mv.y * sCol[tbl * 12 + 3 + c]
                         + mv.z * sCol[tbl * 12 + 6 + c]
                         + mv.w * sCol[tbl * 12 + 9 + c];
                float y = 1.0f / (1.0f + expf(-sv));
                img[(((size_t)b * 3 + c) * 240 + r * 8 + pi) * 256 + ccol * 8 + pj] = y;
            }
        }
    }
}

// ---------------- fp32 fallback image kernel (no ws) -----------------------
__global__ __launch_bounds__(256) void k_image_fp32(const float* __restrict__ A,
                                                    const float* __restrict__ P,
                                                    const float* __restrict__ attr,
                                                    const float* __restrict__ pal,
                                                    float* __restrict__ img) {
    int blk = blockIdx.x;
    int r = blk % 30;
    int b = blk / 30;
    int t0 = r * 32;

    __shared__ float sA[32][33];
    __shared__ float sB[32][256];
    __shared__ float sColF[16][12];

    int tid = threadIdx.x;
    if (tid < 192) {
        int tbl = tid / 12;
        int gc  = tid % 12;
        int tb  = (r >> 1) * 16 + tbl;
        const float* at = attr + ((size_t)b * 240 + tb) * 8;
        const float* pl = pal + (size_t)b * 96 + gc;
        float s = 0.f;
        #pragma unroll
        for (int e = 0; e < 8; e++) s += at[e] * pl[e * 12];
        sColF[tbl][gc] = s;
    }

    float acc[8][4];
    #pragma unroll
    for (int i = 0; i < 8; i++)
        #pragma unroll
        for (int j = 0; j < 4; j++) acc[i][j] = 0.f;

    int tf = tid & 63;
    int tm = tid >> 6;

    const float* Ab = A + ((size_t)b * 960 + t0) * 256;
    const float* Pb = P + (size_t)b * 65536;

    for (int k0 = 0; k0 < 256; k0 += 32) {
        __syncthreads();
        #pragma unroll
        for (int i = 0; i < 4; i++) {
            int li = tid + i * 256;
            int tl = li >> 5, kk = li & 31;
            sA[tl][kk] = Ab[(size_t)tl * 256 + k0 + kk];
        }
        #pragma unroll
        for (int i = 0; i < 8; i++) {
            int li = tid + i * 256;
            int kk = li >> 6, ff = (li & 63) * 4;
            *(float4*)&sB[kk][ff] = *(const float4*)&Pb[(size_t)(k0 + kk) * 256 + ff];
        }
        __syncthreads();
        #pragma unroll
        for (int kk = 0; kk < 32; kk++) {
            float4 bv = *(float4*)&sB[kk][tf * 4];
            #pragma unroll
            for (int i = 0; i < 8; i++) {
                float av = sA[tm * 8 + i][kk];
                acc[i][0] += av * bv.x;
                acc[i][1] += av * bv.y;
                acc[i][2] += av * bv.z;
                acc[i][3] += av * bv.w;
            }
        }
    }

    int pi = tf >> 3, pj = tf & 7;
    #pragma unroll
    for (int i = 0; i < 8; i++) {
        int cc  = tm * 8 + i;
        int tbl = cc >> 1;
        #pragma unroll
        for (int c = 0; c < 3; c++) {
            float s = acc[i][0] * sColF[tbl][c]
                    + acc[i][1] * sColF[tbl][3 + c]
                    + acc[i][2] * sColF[tbl][6 + c]
                    + acc[i][3] * sColF[tbl][9 + c];
            float y = 1.0f / (1.0f + expf(-s));
            img[(((size_t)b * 3 + c) * 240 + r * 8 + pi) * 256 + cc * 8 + pj] = y;
        }
    }
}

extern "C" void kernel_launch(void* const* d_in, const int* in_sizes, int n_in,
                              void* d_out, int out_size, void* d_ws, size_t ws_size,
                              hipStream_t stream) {
    const float* names       = (const float*)d_in[0];
    const float* patterns    = (const float*)d_in[1];
    const float* attributes  = (const float*)d_in[2];
    const float* palettes    = (const float*)d_in[3];
    const float* gumbel_n    = (const float*)d_in[4];
    const float* gumbel_a    = (const float*)d_in[5];
    float* out = (float*)d_out;

    float* out_img   = out + O_IMG;
    float* out_names = out + O_NAMES;
    float* out_p     = out + O_P;
    float* out_attr  = out + O_ATTR;
    float* out_pal   = out + O_PAL;

    const size_t PT_BYTES = 128ULL * 256 * 256 * 2;   // 16.78 MB bf16 P^T
    bool use_mfma = (ws_size >= PT_BYTES) && (d_ws != nullptr);

    if (use_mfma) {
        unsigned short* Pt = (unsigned short*)d_ws;
        k_pattern_t<true><<<8192, 256, 0, stream>>>(patterns, out_p, Pt);
        k_attr<<<120, 256, 0, stream>>>(attributes, gumbel_a, palettes, out_attr, out_pal);
        k_fused<<<1920, 256, 0, stream>>>(names, gumbel_n, Pt, out_attr, palettes,
                                          out_names, out_img);
    } else {
        k_pattern_t<false><<<8192, 256, 0, stream>>>(patterns, out_p, nullptr);
        k_names<<<128 * 60, 256, 0, stream>>>(names, gumbel_n, out_names);
        k_attr<<<120, 256, 0, stream>>>(attributes, gumbel_a, palettes, out_attr, out_pal);
        k_image_fp32<<<128 * 30, 256, 0, stream>>>(out_names, out_p, out_attr, palettes, out_img);
    }
}